// Round 2
// baseline (1440.409 us; speedup 1.0000x reference)
//
#include <hip/hip_runtime.h>
#include <math.h>

#define NLEV 12
#define TSIZE (1u << 19)
#define TMASK (TSIZE - 1u)
#define DOUT 257
#define PPB 256            // points per block (fused fallback)
#define EMB 24             // L*F feature dim
#define RSTRIDE 28         // fused fallback emb row stride
#define TP 128             // points per tile in head kernel

struct ResArr { float r[NLEV]; };

// =====================================================================
// Phase A: level-plane hash-grid encode. One thread per (point, level).
// 1D grid dispatched level-major: lvl = blockIdx.x / nbpl, so at any
// instant all CUs gather into ONE level's 4 MB table == per-XCD L2 size
// -> gathers become L2 hits instead of L3/HBM (round-0 FETCH was 1.6GB).
// 8 independent gathers per thread, no dependent level chain, ~40 VGPR.
// Stores are plane-major float2 -> perfectly coalesced.
// =====================================================================
__global__ __launch_bounds__(256)
void encode_kernel(const float* __restrict__ xin,
                   const float* __restrict__ tables,
                   float2* __restrict__ emb2,
                   int N, int nbpl, ResArr res)
{
    const int lvl = blockIdx.x / nbpl;            // scalar div, once per block
    const int bx  = blockIdx.x - lvl * nbpl;
    const int p   = bx * 256 + threadIdx.x;
    if (p >= N) return;

    const float px = xin[3 * p + 0];
    const float py = xin[3 * p + 1];
    const float pz = xin[3 * p + 2];

    const float rf = res.r[lvl];
    const float sx = px * rf, sy = py * rf, sz = pz * rf;
    const float gx = floorf(sx), gy = floorf(sy), gz = floorf(sz);
    const float tx = sx - gx, ty = sy - gy, tz = sz - gz;
    const unsigned ix = (unsigned)gx, iy = (unsigned)gy, iz = (unsigned)gz;
    // primes: {1, 2654435761, 805459861}; uint32 wraparound
    const unsigned hx0 = ix,               hx1 = ix + 1u;
    const unsigned hy0 = iy * 2654435761u, hy1 = hy0 + 2654435761u;
    const unsigned hz0 = iz * 805459861u,  hz1 = hz0 + 805459861u;
    const float2* __restrict__ tab = (const float2*)tables + (size_t)lvl * TSIZE;
    // 8 fully independent gathers -> max MLP per wave
    float2 f0 = tab[(hx0 ^ hy0 ^ hz0) & TMASK];
    float2 f1 = tab[(hx0 ^ hy0 ^ hz1) & TMASK];
    float2 f2 = tab[(hx0 ^ hy1 ^ hz0) & TMASK];
    float2 f3 = tab[(hx0 ^ hy1 ^ hz1) & TMASK];
    float2 f4 = tab[(hx1 ^ hy0 ^ hz0) & TMASK];
    float2 f5 = tab[(hx1 ^ hy0 ^ hz1) & TMASK];
    float2 f6 = tab[(hx1 ^ hy1 ^ hz0) & TMASK];
    float2 f7 = tab[(hx1 ^ hy1 ^ hz1) & TMASK];
    const float u0 = 1.0f - tx, u1 = tx;
    const float v0 = 1.0f - ty, v1 = ty;
    const float s0 = 1.0f - tz, s1 = tz;
    const float w0 = (u0 * v0) * s0;
    const float w1 = (u0 * v0) * s1;
    const float w2 = (u0 * v1) * s0;
    const float w3 = (u0 * v1) * s1;
    const float w4 = (u1 * v0) * s0;
    const float w5 = (u1 * v0) * s1;
    const float w6 = (u1 * v1) * s0;
    const float w7 = (u1 * v1) * s1;
    float a = w0 * f0.x;
    float b = w0 * f0.y;
    a = fmaf(w1, f1.x, a);  b = fmaf(w1, f1.y, b);
    a = fmaf(w2, f2.x, a);  b = fmaf(w2, f2.y, b);
    a = fmaf(w3, f3.x, a);  b = fmaf(w3, f3.y, b);
    a = fmaf(w4, f4.x, a);  b = fmaf(w4, f4.y, b);
    a = fmaf(w5, f5.x, a);  b = fmaf(w5, f5.y, b);
    a = fmaf(w6, f6.x, a);  b = fmaf(w6, f6.y, b);
    a = fmaf(w7, f7.x, a);  b = fmaf(w7, f7.y, b);
    emb2[(size_t)lvl * N + p] = make_float2(a, b);
}

// =====================================================================
// Phase B: head GEMV, no LDS at all. Thread j owns output column j for
// all TP points of its tile. Per-point emb values are wave-uniform in
// the n-loop -> broadcast global loads (1 line request per instr, L1/L2
// hit: each point is read by exactly one block, freshly written by
// encode). Store pipe (539 MB coalesced stream) is the intended limiter.
// Column 256: per-lane coalesced tail, W offsets compile-time-constant
// -> scalar cache.
// =====================================================================
__global__ __launch_bounds__(256)
void head_kernel(const float2* __restrict__ emb2,
                 const float* __restrict__ Wm,
                 const float* __restrict__ bias,
                 float* __restrict__ out,
                 int N)
{
    const int tid  = threadIdx.x;
    const int base = blockIdx.x * TP;
    const int nv   = min(TP, N - base);

    // W column for j = tid (coalesced: lane t reads W[k*257 + t])
    float wcol[EMB];
#pragma unroll
    for (int k = 0; k < EMB; ++k) wcol[k] = Wm[k * DOUT + tid];
    const float bj = bias[tid];

    float* orow = out + (size_t)base * DOUT + tid;
#pragma unroll 2
    for (int n = 0; n < nv; ++n, orow += DOUT) {
        float accA = bj, accB = 0.0f;     // 2 chains for FMA-latency ILP
#pragma unroll
        for (int l = 0; l < NLEV; ++l) {
            const float2 q = emb2[(size_t)l * N + base + n];  // uniform bcast
            accA = fmaf(q.x, wcol[2 * l + 0], accA);
            accB = fmaf(q.y, wcol[2 * l + 1], accB);
        }
        *orow = accA + accB;
    }

    // column 256: first nv threads, one point each; coalesced emb reads
    if (tid < nv) {
        const int p = base + tid;
        float acc = bias[256];
#pragma unroll
        for (int l = 0; l < NLEV; ++l) {
            const float2 q = emb2[(size_t)l * N + p];
            acc = fmaf(q.x, Wm[(2 * l) * DOUT + 256],
                  fmaf(q.y, Wm[(2 * l + 1) * DOUT + 256], acc));
        }
        out[(size_t)p * DOUT + 256] = acc;
    }
}

// =====================================================================
// Fallback: original fused kernel (known-good), used only if the
// workspace cannot hold the 50.3 MB emb intermediate.
// =====================================================================
__global__ __launch_bounds__(256)
void hashgrid_head_kernel(const float* __restrict__ xin,
                          const float* __restrict__ tables,
                          const float* __restrict__ Wm,
                          const float* __restrict__ bias,
                          float* __restrict__ out,
                          int N, ResArr res)
{
    __shared__ float emb[PPB * RSTRIDE];
    const int tid  = threadIdx.x;
    const int base = blockIdx.x * PPB;
    const int p    = base + tid;

    float wcol[EMB];
#pragma unroll
    for (int k = 0; k < EMB; ++k) wcol[k] = Wm[k * DOUT + tid];
    const float bj = bias[tid];

    const bool extra = (tid < 64);
    float wext[EMB];
    float bext = 0.0f;
    if (extra) {
#pragma unroll
        for (int k = 0; k < EMB; ++k) wext[k] = Wm[k * DOUT + 256];
        bext = bias[256];
    }

    if (p < N) {
        const float px = xin[3 * p + 0];
        const float py = xin[3 * p + 1];
        const float pz = xin[3 * p + 2];
#pragma unroll 2
        for (int l = 0; l < NLEV; ++l) {
            const float rf = res.r[l];
            const float sx = px * rf, sy = py * rf, sz = pz * rf;
            const float gx = floorf(sx), gy = floorf(sy), gz = floorf(sz);
            const float tx = sx - gx, ty = sy - gy, tz = sz - gz;
            const unsigned ix = (unsigned)gx, iy = (unsigned)gy, iz = (unsigned)gz;
            const unsigned hx0 = ix,               hx1 = ix + 1u;
            const unsigned hy0 = iy * 2654435761u, hy1 = hy0 + 2654435761u;
            const unsigned hz0 = iz * 805459861u,  hz1 = hz0 + 805459861u;
            const float2* __restrict__ tab = (const float2*)tables + (size_t)l * TSIZE;
            float2 f0 = tab[(hx0 ^ hy0 ^ hz0) & TMASK];
            float2 f1 = tab[(hx0 ^ hy0 ^ hz1) & TMASK];
            float2 f2 = tab[(hx0 ^ hy1 ^ hz0) & TMASK];
            float2 f3 = tab[(hx0 ^ hy1 ^ hz1) & TMASK];
            float2 f4 = tab[(hx1 ^ hy0 ^ hz0) & TMASK];
            float2 f5 = tab[(hx1 ^ hy0 ^ hz1) & TMASK];
            float2 f6 = tab[(hx1 ^ hy1 ^ hz0) & TMASK];
            float2 f7 = tab[(hx1 ^ hy1 ^ hz1) & TMASK];
            const float u0 = 1.0f - tx, u1 = tx;
            const float v0 = 1.0f - ty, v1 = ty;
            const float s0 = 1.0f - tz, s1 = tz;
            const float w0 = (u0 * v0) * s0;
            const float w1 = (u0 * v0) * s1;
            const float w2 = (u0 * v1) * s0;
            const float w3 = (u0 * v1) * s1;
            const float w4 = (u1 * v0) * s0;
            const float w5 = (u1 * v0) * s1;
            const float w6 = (u1 * v1) * s0;
            const float w7 = (u1 * v1) * s1;
            float a = w0 * f0.x;
            float b = w0 * f0.y;
            a = fmaf(w1, f1.x, a);  b = fmaf(w1, f1.y, b);
            a = fmaf(w2, f2.x, a);  b = fmaf(w2, f2.y, b);
            a = fmaf(w3, f3.x, a);  b = fmaf(w3, f3.y, b);
            a = fmaf(w4, f4.x, a);  b = fmaf(w4, f4.y, b);
            a = fmaf(w5, f5.x, a);  b = fmaf(w5, f5.y, b);
            a = fmaf(w6, f6.x, a);  b = fmaf(w6, f6.y, b);
            a = fmaf(w7, f7.x, a);  b = fmaf(w7, f7.y, b);
            *(float2*)&emb[tid * RSTRIDE + 2 * l] = make_float2(a, b);
        }
    }

    __syncthreads();

    const int nvalid = min(PPB, N - base);
    for (int n = 0; n < nvalid; ++n) {
        const float4* e4 = (const float4*)&emb[n * RSTRIDE];
        float4 q0 = e4[0], q1 = e4[1], q2 = e4[2], q3 = e4[3], q4 = e4[4], q5 = e4[5];
        float e[EMB] = {q0.x, q0.y, q0.z, q0.w, q1.x, q1.y, q1.z, q1.w,
                        q2.x, q2.y, q2.z, q2.w, q3.x, q3.y, q3.z, q3.w,
                        q4.x, q4.y, q4.z, q4.w, q5.x, q5.y, q5.z, q5.w};
        float acc = bj;
#pragma unroll
        for (int k = 0; k < EMB; ++k) acc = fmaf(e[k], wcol[k], acc);
        out[(size_t)(base + n) * DOUT + tid] = acc;
        if (extra) {
            float acc2 = bext;
#pragma unroll
            for (int k = 0; k < EMB; ++k) acc2 = fmaf(e[k], wext[k], acc2);
            if (tid == 0) out[(size_t)(base + n) * DOUT + 256] = acc2;
        }
    }
}

extern "C" void kernel_launch(void* const* d_in, const int* in_sizes, int n_in,
                              void* d_out, int out_size, void* d_ws, size_t ws_size,
                              hipStream_t stream) {
    const float* xin    = (const float*)d_in[0];
    const float* tables = (const float*)d_in[1];
    const float* Wm     = (const float*)d_in[2];
    const float* bias   = (const float*)d_in[3];
    float* out = (float*)d_out;
    const int N = in_sizes[0] / 3;

    // Replicate numpy: RES = floor(BASE_RES * growth**arange(L)).
    ResArr res;
    const double growth = exp((log(2048.0) - log(16.0)) / 11.0);
    for (int l = 0; l < NLEV; ++l)
        res.r[l] = (float)floor(16.0 * pow(growth, (double)l));

    const size_t need = (size_t)NLEV * (size_t)N * sizeof(float2);
    if (d_ws != nullptr && ws_size >= need) {
        float2* emb2 = (float2*)d_ws;
        const int nbpl = (N + 255) / 256;
        hipLaunchKernelGGL(encode_kernel, dim3(nbpl * NLEV), dim3(256), 0, stream,
                           xin, tables, emb2, N, nbpl, res);
        hipLaunchKernelGGL(head_kernel, dim3((N + TP - 1) / TP), dim3(256), 0, stream,
                           emb2, Wm, bias, out, N);
    } else {
        const int grid = (N + PPB - 1) / PPB;
        hipLaunchKernelGGL(hashgrid_head_kernel, dim3(grid), dim3(PPB), 0, stream,
                           xin, tables, Wm, bias, out, N, res);
    }
}

// Round 3
// 821.551 us; speedup vs baseline: 1.7533x; 1.7533x over previous
//
#include <hip/hip_runtime.h>
#include <math.h>

#define NLEV 12
#define TSIZE (1u << 19)
#define TMASK (TSIZE - 1u)
#define DOUT 257
#define PPB 256            // points per block (fused fallback)
#define EMB 24             // L*F feature dim
#define RSTRIDE 28         // fused fallback emb row stride
#define TP 128             // points per tile in head kernel
#define EPT 2              // encode: points per thread
#define EPB (256 * EPT)    // encode: points per block

struct ResArr { float r[NLEV]; };

// ---------------------------------------------------------------------
// Per-point hash-corner computation: 8 table indices + 8 trilinear
// weights. Arithmetic order kept identical to the verified kernels.
// ---------------------------------------------------------------------
struct Corner { unsigned idx[8]; float w[8]; };

__device__ __forceinline__ void hash_corners(float rf, float px, float py, float pz,
                                             Corner& c)
{
    const float sx = px * rf, sy = py * rf, sz = pz * rf;
    const float gx = floorf(sx), gy = floorf(sy), gz = floorf(sz);
    const float tx = sx - gx, ty = sy - gy, tz = sz - gz;
    const unsigned ix = (unsigned)gx, iy = (unsigned)gy, iz = (unsigned)gz;
    // primes: {1, 2654435761, 805459861}; uint32 wraparound
    const unsigned hx0 = ix,               hx1 = ix + 1u;
    const unsigned hy0 = iy * 2654435761u, hy1 = hy0 + 2654435761u;
    const unsigned hz0 = iz * 805459861u,  hz1 = hz0 + 805459861u;
    c.idx[0] = (hx0 ^ hy0 ^ hz0) & TMASK;
    c.idx[1] = (hx0 ^ hy0 ^ hz1) & TMASK;
    c.idx[2] = (hx0 ^ hy1 ^ hz0) & TMASK;
    c.idx[3] = (hx0 ^ hy1 ^ hz1) & TMASK;
    c.idx[4] = (hx1 ^ hy0 ^ hz0) & TMASK;
    c.idx[5] = (hx1 ^ hy0 ^ hz1) & TMASK;
    c.idx[6] = (hx1 ^ hy1 ^ hz0) & TMASK;
    c.idx[7] = (hx1 ^ hy1 ^ hz1) & TMASK;
    const float u0 = 1.0f - tx, u1 = tx;
    const float v0 = 1.0f - ty, v1 = ty;
    const float s0 = 1.0f - tz, s1 = tz;
    c.w[0] = (u0 * v0) * s0;
    c.w[1] = (u0 * v0) * s1;
    c.w[2] = (u0 * v1) * s0;
    c.w[3] = (u0 * v1) * s1;
    c.w[4] = (u1 * v0) * s0;
    c.w[5] = (u1 * v0) * s1;
    c.w[6] = (u1 * v1) * s0;
    c.w[7] = (u1 * v1) * s1;
}

// =====================================================================
// Phase A: level-plane hash-grid encode, TWO points per thread.
// 1D grid dispatched level-major (lvl = blockIdx.x / nbpl): at any
// instant all CUs gather into ONE level's 4 MB table == per-XCD L2 size
// (confirmed round 2: encode ~430 -> ~290 us). Still latency-bound:
// 2 points/thread doubles independent in-flight gathers per wave (16),
// ~80 VGPR -> 6 waves/SIMD -> ~96 gathers in flight per SIMD (+50%).
// Both points same level -> L2 working set unchanged. Stores coalesced.
// =====================================================================
__global__ __launch_bounds__(256)
void encode_kernel(const float* __restrict__ xin,
                   const float* __restrict__ tables,
                   float2* __restrict__ emb2,
                   int N, int nbpl, ResArr res)
{
    const int lvl = blockIdx.x / nbpl;            // scalar div, once per block
    const int bx  = blockIdx.x - lvl * nbpl;
    const int pA  = bx * EPB + threadIdx.x;       // point A
    const int pB  = pA + 256;                     // point B
    if (pA >= N) return;
    const bool hasB = (pB < N);

    const float ax = xin[3 * pA + 0];
    const float ay = xin[3 * pA + 1];
    const float az = xin[3 * pA + 2];
    float bx_ = 0.f, by_ = 0.f, bz_ = 0.f;
    if (hasB) {
        bx_ = xin[3 * pB + 0];
        by_ = xin[3 * pB + 1];
        bz_ = xin[3 * pB + 2];
    }

    const float rf = res.r[lvl];
    Corner cA, cB;
    hash_corners(rf, ax, ay, az, cA);
    hash_corners(rf, bx_, by_, bz_, cB);

    const float2* __restrict__ tab = (const float2*)tables + (size_t)lvl * TSIZE;

    // 16 independent gathers issued back-to-back -> max MLP per wave
    float2 fA[8], fB[8];
#pragma unroll
    for (int i = 0; i < 8; ++i) fA[i] = tab[cA.idx[i]];
#pragma unroll
    for (int i = 0; i < 8; ++i) fB[i] = tab[cB.idx[i]];

    // point A reduction (same FMA order as verified kernel)
    float a = cA.w[0] * fA[0].x;
    float b = cA.w[0] * fA[0].y;
#pragma unroll
    for (int i = 1; i < 8; ++i) {
        a = fmaf(cA.w[i], fA[i].x, a);
        b = fmaf(cA.w[i], fA[i].y, b);
    }
    emb2[(size_t)lvl * N + pA] = make_float2(a, b);

    if (hasB) {
        float a2 = cB.w[0] * fB[0].x;
        float b2 = cB.w[0] * fB[0].y;
#pragma unroll
        for (int i = 1; i < 8; ++i) {
            a2 = fmaf(cB.w[i], fB[i].x, a2);
            b2 = fmaf(cB.w[i], fB[i].y, b2);
        }
        emb2[(size_t)lvl * N + pB] = make_float2(a2, b2);
    }
}

// =====================================================================
// Phase B: head GEMV (round-1 proven version). 12 KB LDS tile (TP=128
// points), coalesced SoA stage, broadcast-only ds_read_b64 in the inner
// loop (conflict-free, short pipelined latency -- NOT the scalar-load
// serialization that cost 810 us in round 2). Thread j owns column j.
// Column 256: per-lane tail from LDS, W offsets compile-time-constant.
// ~32 VGPR + 12 KB LDS -> 8 blocks/CU (32 waves).
// =====================================================================
__global__ __launch_bounds__(256)
void head_kernel(const float2* __restrict__ emb2,
                 const float* __restrict__ Wm,
                 const float* __restrict__ bias,
                 float* __restrict__ out,
                 int N)
{
    __shared__ float2 sm[NLEV][TP];       // 12288 B
    const int tid  = threadIdx.x;
    const int base = blockIdx.x * TP;
    const int nv   = min(TP, N - base);

    // W column for j = tid (coalesced: lane t reads W[k*257 + t])
    float wcol[EMB];
#pragma unroll
    for (int k = 0; k < EMB; ++k) wcol[k] = Wm[k * DOUT + tid];
    const float bj = bias[tid];

    // stage emb tile: 1536 float2, 256 threads -> 6 coalesced iters
#pragma unroll
    for (int i = 0; i < (NLEV * TP) / 256; ++i) {
        const int f = i * 256 + tid;
        const int l = f >> 7;             // TP == 128
        const int n = f & (TP - 1);
        if (n < nv) sm[l][n] = emb2[(size_t)l * N + base + n];
    }
    __syncthreads();

    float* orow = out + (size_t)base * DOUT + tid;
    for (int n = 0; n < nv; ++n, orow += DOUT) {
        float accA = bj, accB = 0.0f;     // 2 chains for FMA-latency ILP
#pragma unroll
        for (int l = 0; l < NLEV; l += 2) {
            const float2 q0 = sm[l][n];
            const float2 q1 = sm[l + 1][n];
            accA = fmaf(q0.x, wcol[2 * l + 0], accA);
            accB = fmaf(q0.y, wcol[2 * l + 1], accB);
            accA = fmaf(q1.x, wcol[2 * l + 2], accA);
            accB = fmaf(q1.y, wcol[2 * l + 3], accB);
        }
        *orow = accA + accB;
    }

    // column 256 for this tile: first nv threads, one point each.
    if (tid < nv) {
        float acc = bias[256];
#pragma unroll
        for (int l = 0; l < NLEV; ++l) {
            const float2 q = sm[l][tid];
            acc = fmaf(q.x, Wm[(2 * l) * DOUT + 256],
                  fmaf(q.y, Wm[(2 * l + 1) * DOUT + 256], acc));
        }
        out[(size_t)(base + tid) * DOUT + 256] = acc;
    }
}

// =====================================================================
// Fallback: original fused kernel (known-good), used only if the
// workspace cannot hold the 50.3 MB emb intermediate.
// =====================================================================
__global__ __launch_bounds__(256)
void hashgrid_head_kernel(const float* __restrict__ xin,
                          const float* __restrict__ tables,
                          const float* __restrict__ Wm,
                          const float* __restrict__ bias,
                          float* __restrict__ out,
                          int N, ResArr res)
{
    __shared__ float emb[PPB * RSTRIDE];
    const int tid  = threadIdx.x;
    const int base = blockIdx.x * PPB;
    const int p    = base + tid;

    float wcol[EMB];
#pragma unroll
    for (int k = 0; k < EMB; ++k) wcol[k] = Wm[k * DOUT + tid];
    const float bj = bias[tid];

    const bool extra = (tid < 64);
    float wext[EMB];
    float bext = 0.0f;
    if (extra) {
#pragma unroll
        for (int k = 0; k < EMB; ++k) wext[k] = Wm[k * DOUT + 256];
        bext = bias[256];
    }

    if (p < N) {
        const float px = xin[3 * p + 0];
        const float py = xin[3 * p + 1];
        const float pz = xin[3 * p + 2];
#pragma unroll 2
        for (int l = 0; l < NLEV; ++l) {
            const float rf = res.r[l];
            Corner c;
            hash_corners(rf, px, py, pz, c);
            const float2* __restrict__ tab = (const float2*)tables + (size_t)l * TSIZE;
            float2 f[8];
#pragma unroll
            for (int i = 0; i < 8; ++i) f[i] = tab[c.idx[i]];
            float a = c.w[0] * f[0].x;
            float b = c.w[0] * f[0].y;
#pragma unroll
            for (int i = 1; i < 8; ++i) {
                a = fmaf(c.w[i], f[i].x, a);
                b = fmaf(c.w[i], f[i].y, b);
            }
            *(float2*)&emb[tid * RSTRIDE + 2 * l] = make_float2(a, b);
        }
    }

    __syncthreads();

    const int nvalid = min(PPB, N - base);
    for (int n = 0; n < nvalid; ++n) {
        const float4* e4 = (const float4*)&emb[n * RSTRIDE];
        float4 q0 = e4[0], q1 = e4[1], q2 = e4[2], q3 = e4[3], q4 = e4[4], q5 = e4[5];
        float e[EMB] = {q0.x, q0.y, q0.z, q0.w, q1.x, q1.y, q1.z, q1.w,
                        q2.x, q2.y, q2.z, q2.w, q3.x, q3.y, q3.z, q3.w,
                        q4.x, q4.y, q4.z, q4.w, q5.x, q5.y, q5.z, q5.w};
        float acc = bj;
#pragma unroll
        for (int k = 0; k < EMB; ++k) acc = fmaf(e[k], wcol[k], acc);
        out[(size_t)(base + n) * DOUT + tid] = acc;
        if (extra) {
            float acc2 = bext;
#pragma unroll
            for (int k = 0; k < EMB; ++k) acc2 = fmaf(e[k], wext[k], acc2);
            if (tid == 0) out[(size_t)(base + n) * DOUT + 256] = acc2;
        }
    }
}

extern "C" void kernel_launch(void* const* d_in, const int* in_sizes, int n_in,
                              void* d_out, int out_size, void* d_ws, size_t ws_size,
                              hipStream_t stream) {
    const float* xin    = (const float*)d_in[0];
    const float* tables = (const float*)d_in[1];
    const float* Wm     = (const float*)d_in[2];
    const float* bias   = (const float*)d_in[3];
    float* out = (float*)d_out;
    const int N = in_sizes[0] / 3;

    // Replicate numpy: RES = floor(BASE_RES * growth**arange(L)).
    ResArr res;
    const double growth = exp((log(2048.0) - log(16.0)) / 11.0);
    for (int l = 0; l < NLEV; ++l)
        res.r[l] = (float)floor(16.0 * pow(growth, (double)l));

    const size_t need = (size_t)NLEV * (size_t)N * sizeof(float2);
    if (d_ws != nullptr && ws_size >= need) {
        float2* emb2 = (float2*)d_ws;
        const int nbpl = (N + EPB - 1) / EPB;
        hipLaunchKernelGGL(encode_kernel, dim3(nbpl * NLEV), dim3(256), 0, stream,
                           xin, tables, emb2, N, nbpl, res);
        hipLaunchKernelGGL(head_kernel, dim3((N + TP - 1) / TP), dim3(256), 0, stream,
                           emb2, Wm, bias, out, N);
    } else {
        const int grid = (N + PPB - 1) / PPB;
        hipLaunchKernelGGL(hashgrid_head_kernel, dim3(grid), dim3(PPB), 0, stream,
                           xin, tables, Wm, bias, out, N, res);
    }
}